// Round 7
// baseline (136.657 us; speedup 1.0000x reference)
//
#include <hip/hip_runtime.h>
#include <math.h>

// Problem constants (match reference)
constexpr int TPC    = 8;       // TP
constexpr int NNODES = 100000;
constexpr int BATCH  = 128;
constexpr int DMAX   = 64;
constexpr int Hc     = 15;
constexpr int Kc     = 15;
constexpr int NCAND  = Hc * Kc + 1;   // 226

// The reference lut is jnp.floor(jnp.log2(x))+1 computed in FLOAT32 via
// log(x)/log(2). Non-powers-of-two are >=4.4e-5 away from an integer (safe
// vs ~1e-6 rounding noise), but at x=2^k the true log2 is exactly k and f32
// noise can round DOWN -> lut[2^k] may be k instead of k+1. So we use
// 32-__clz(x) for non-powers and the ACTUAL lut data for the 16 entries
// x in {0,1,2,4,...,2^14}. (R1/R4 failed deterministically - identical
// absmax in f32 and f64 - because clz diverged from the real lut there.)

__device__ __forceinline__ int bl_of(int x, const int* __restrict__ powlut) {
    const int idx = 32 - __clz(x);              // bit_length(x), 0 for x=0
    return ((x & (x - 1)) == 0) ? powlut[idx] : idx;
}

__global__ void copy_kernel(const int* __restrict__ loc, float* __restrict__ out) {
    int i = blockIdx.x * blockDim.x + threadIdx.x;
    if (i < 3) out[i] = 0.0f;   // zero the 3 loss accumulators
    const int total = NNODES * TPC;
    for (int idx = i; idx < total; idx += gridDim.x * blockDim.x)
        out[3 + idx] = (float)loc[idx];
}

__launch_bounds__(256)
__global__ void main_kernel(const float* __restrict__ lut,
                            const int* __restrict__ sta_ind,
                            const int* __restrict__ locations,
                            const int* __restrict__ degree,
                            const int* __restrict__ pos_ind,
                            const int* __restrict__ neg_ind,
                            const int* __restrict__ rmasks,
                            const int* __restrict__ perm,
                            float* __restrict__ out) {
    // Per-(b,t) block. Loss arithmetic in f64 (exact small-int inputs ->
    // ordering noise ~1e-14, below any reference's resolution).
    __shared__ double Tp[64][16];         // pos loss term, indexed [d][g]
    __shared__ double Tn[64][16];         // neg loss term
    __shared__ int    ploc[64], nloc[64]; // t-th component of neighbor locations (-1 if invalid)
    __shared__ int    Sarr[2][64];        // dis_sta_{pos,neg}um (int, exact)
    __shared__ double Larr[2][64];        // log((deg1+1)*(deg2+1))
    __shared__ int    dsarr[2][64];       // dis_sta_{pos,neg}[t]
    __shared__ int    varr[2][64];        // validity
    __shared__ int    sh_sta[8];
    __shared__ int    powlut[16];         // actual lut values at x=0 and x=2^(i-1)
    __shared__ double lg_sh;
    __shared__ double cpos[256], cneg[256];
    __shared__ int    cval_sh[256];
    __shared__ double wmin[4];
    __shared__ int    widx[4];

    const int b   = blockIdx.x >> 3;
    const int t   = blockIdx.x & 7;
    const int tid = threadIdx.x;
    const int sta = sta_ind[b];

    if (tid < 8) sh_sta[tid] = locations[sta * 8 + tid];
    // powlut[0] = lut[0] (=0); powlut[i] = lut[2^(i-1)] for i=1..15
    // (index i corresponds to bit_length value i at x = 2^(i-1))
    if (tid >= 16 && tid < 32) {
        const int i = tid - 16;
        powlut[i] = (i == 0) ? (int)lut[0] : (int)lut[1 << (i - 1)];
    }
    __syncthreads();

    // ---- step 1: per-d quantities (threads 0..63 pos, 64..127 neg) ----
    if (tid < 128) {
        const int which = tid >> 6;           // 0 = pos, 1 = neg
        const int d     = tid & 63;
        const int* ind  = which ? neg_ind : pos_ind;
        const int pi    = ind[b * DMAX + d];
        const int valid = (pi >= 0) ? 1 : 0;
        const int piw   = valid ? pi : pi + NNODES;   // -1 -> NNODES-1
        const int deg1  = degree[sta];
        const int deg2  = degree[piw];
        const double L  = log((double)((deg1 + 1) * (deg2 + 1)));
        int Si = 0, dsi = 0, lc = -1;
        if (valid) {
            #pragma unroll
            for (int tt = 0; tt < 8; ++tt) {
                const int l  = locations[pi * 8 + tt];
                const int x  = sh_sta[tt] ^ l;
                const int bl = bl_of(x, powlut);
                Si += bl;
                if (tt == t) { dsi = bl; lc = l; }
            }
        }
        Sarr[which][d]  = Si;
        Larr[which][d]  = L;
        dsarr[which][d] = dsi;
        varr[which][d]  = valid;
        if (which == 0) ploc[d] = lc; else nloc[d] = lc;
        if (which == 0) {   // wave 0 exactly
            unsigned long long m = __ballot(valid);
            if (tid == 0) lg_sh = (double)__popcll(m);
        }
    }
    __syncthreads();

    // ---- step 2: fill 64x16 term tables (2048 log evals / block, f64) ----
    for (int e = tid; e < 2048; e += 256) {
        const int which = e >> 10;
        const int rem   = e & 1023;
        const int d     = rem >> 4;
        const int g     = rem & 15;
        const double L  = Larr[which][d];
        double x;
        if (varr[which][d])
            x = (double)(g - dsarr[which][d] + Sarr[which][d]) * 0.125;  // /TP, exact
        else
            x = which ? 1000.0 : 0.0;   // reference fill values
        const double aa   = (x + 0.1) / L;
        const double p    = 1.0 / (1.0 + aa * aa);
        const double term = which ? -log(1.0 + 0.1 - p) : -log(p);
        if (which) Tn[d][g] = term; else Tp[d][g] = term;
    }
    __syncthreads();

    // ---- step 3: one candidate per thread, sequential d-loop ----
    const int c = tid;
    double v = __builtin_inf();
    double plc = 0.0, nlc = 0.0;
    int cval = 0;
    if (c < NCAND) {
        const int q  = perm[c];
        const int st = sh_sta[t];
        if (q < NCAND - 1) {
            const int h = q / Kc, k = q % Kc;
            cval = st ^ (1 << h) ^ rmasks[((b * Hc + h) * Kc + k) * 8 + t];
        } else {
            cval = st;
        }
        double ps = 0.0, ns = 0.0;
        #pragma unroll 4
        for (int d = 0; d < 64; ++d) {
            const int xp = (cval ^ ploc[d]) & 0x7FFF;   // invalid rows: constant table row
            ps += Tp[d][bl_of(xp, powlut)];
            const int xn = (cval ^ nloc[d]) & 0x7FFF;
            ns += Tn[d][bl_of(xn, powlut)];
        }
        const double lg = lg_sh;
        plc = ps / lg;            // pos_loss
        nlc = ns / lg;            // neg_loss
        v   = plc + nlc;          // total_loss (POS_RATIO == 1)
    }
    cpos[tid]    = plc;
    cneg[tid]    = nlc;
    cval_sh[tid] = cval;

    // ---- step 4: argmin over candidates (first-index tie-break) ----
    int idx = tid;
    #pragma unroll
    for (int m = 32; m >= 1; m >>= 1) {
        const double ov = __shfl_xor(v, m, 64);
        const int    oi = __shfl_xor(idx, m, 64);
        if (ov < v || (ov == v && oi < idx)) { v = ov; idx = oi; }
    }
    if ((tid & 63) == 0) { wmin[tid >> 6] = v; widx[tid >> 6] = idx; }
    __syncthreads();

    if (tid == 0) {
        double bv = wmin[0];
        int    bi = widx[0];
        #pragma unroll
        for (int w = 1; w < 4; ++w) {
            const double vv = wmin[w];
            const int    ii = widx[w];
            if (vv < bv || (vv == bv && ii < bi)) { bv = vv; bi = ii; }
        }
        const double inv = 1.0 / 1024.0;   // mean over BATCH*TP selected values
        atomicAdd(out + 0, (float)(bv * inv));
        atomicAdd(out + 1, (float)(cpos[bi] * inv));
        atomicAdd(out + 2, (float)(cneg[bi] * inv));
        out[3 + sta * 8 + t] = (float)cval_sh[bi];   // selected location component
    }
}

extern "C" void kernel_launch(void* const* d_in, const int* in_sizes, int n_in,
                              void* d_out, int out_size, void* d_ws, size_t ws_size,
                              hipStream_t stream) {
    // setup_inputs order: lut, sta_ind, locations, degree, pos_ind, neg_ind, random_masks, perm
    const float* lut     = (const float*)d_in[0];
    const int* sta_ind   = (const int*)d_in[1];
    const int* locations = (const int*)d_in[2];
    const int* degree    = (const int*)d_in[3];
    const int* pos_ind   = (const int*)d_in[4];
    const int* neg_ind   = (const int*)d_in[5];
    const int* rmasks    = (const int*)d_in[6];
    const int* perm      = (const int*)d_in[7];
    float* out = (float*)d_out;

    hipLaunchKernelGGL(copy_kernel, dim3(1024), dim3(256), 0, stream, locations, out);
    hipLaunchKernelGGL(main_kernel, dim3(BATCH * TPC), dim3(256), 0, stream,
                       lut, sta_ind, locations, degree, pos_ind, neg_ind, rmasks, perm, out);
}

// Round 8
// 126.448 us; speedup vs baseline: 1.0807x; 1.0807x over previous
//
#include <hip/hip_runtime.h>
#include <math.h>

// Problem constants (match reference)
constexpr int TPC    = 8;       // TP
constexpr int NNODES = 100000;
constexpr int BATCH  = 128;
constexpr int DMAX   = 64;
constexpr int Hc     = 15;
constexpr int Kc     = 15;
constexpr int NCAND  = Hc * Kc + 1;   // 226

// lut[x] = f32 floor(log2(x))+1. At x=2^k a 1-ulp-low log2 can make the
// entry k instead of k+1, so the 16 entries at x in {0,1,2,4,...,2^14} are
// read from the REAL lut input (powlut); everything else is 32-__clz(x).
// (R1-R4 failed deterministically with identical absmax in f32 and f64 ->
// data divergence, fixed in R7 which passed with absmax 0.)
//
// R8: all-f32 (R1==R4 bit-identical absmax proved f32 noise causes zero
// argmin flips on this dataset), division-free log algebra, and 32-wide
// tables that fold the powlut correction out of the inner loop.

__device__ __forceinline__ int bl_of(int x, const int* __restrict__ powlut) {
    const int idx = 32 - __clz(x);              // bit_length(x), 0 for x=0
    return ((x & (x - 1)) == 0) ? powlut[idx] : idx;
}

__global__ void copy_kernel(const int* __restrict__ loc, float* __restrict__ out) {
    int i = blockIdx.x * blockDim.x + threadIdx.x;
    if (i < 3) out[i] = 0.0f;   // zero the 3 loss accumulators
    const int total = NNODES * TPC;
    for (int idx = i; idx < total; idx += gridDim.x * blockDim.x)
        out[3 + idx] = (float)loc[idx];
}

__launch_bounds__(256)
__global__ void main_kernel(const float* __restrict__ lut,
                            const int* __restrict__ sta_ind,
                            const int* __restrict__ locations,
                            const int* __restrict__ degree,
                            const int* __restrict__ pos_ind,
                            const int* __restrict__ neg_ind,
                            const int* __restrict__ rmasks,
                            const int* __restrict__ perm,
                            float* __restrict__ out) {
    // Per-(b,t) block.
    // Table layout: T[d][g] for g in [0,16) = term at bit-length g (non-pow2
    // path); T[d][16+r] = term at bit-length powlut[r] (pow2 path).
    __shared__ float Tp[64][32];          // pos loss term
    __shared__ float Tn[64][32];          // neg loss term
    __shared__ int   ploc[64], nloc[64];  // t-th component of neighbor locations (-1 if invalid)
    __shared__ int   Sarr[2][64];         // dis_sta_{pos,neg}um (int, exact)
    __shared__ float Lsq[2][64];          // L^2,  L = log((deg1+1)*(deg2+1))
    __shared__ float logLsq[64];          // logf(L^2) for pos rows
    __shared__ int   dsarr[2][64];        // dis_sta_{pos,neg}[t]
    __shared__ int   varr[2][64];         // validity
    __shared__ int   sh_sta[8];
    __shared__ int   powlut[16];          // actual lut at x=0 and x=2^(i-1)
    __shared__ float lg_sh;
    __shared__ float cpos[256], cneg[256];
    __shared__ int   cval_sh[256];
    __shared__ float wmin[4];
    __shared__ int   widx[4];

    const int b   = blockIdx.x >> 3;
    const int t   = blockIdx.x & 7;
    const int tid = threadIdx.x;
    const int sta = sta_ind[b];

    if (tid < 8) sh_sta[tid] = locations[sta * 8 + tid];
    if (tid >= 16 && tid < 32) {
        const int i = tid - 16;
        powlut[i] = (i == 0) ? (int)lut[0] : (int)lut[1 << (i - 1)];
    }
    __syncthreads();

    // ---- step 1: per-d quantities (threads 0..63 pos, 64..127 neg) ----
    if (tid < 128) {
        const int which = tid >> 6;           // 0 = pos, 1 = neg
        const int d     = tid & 63;
        const int* ind  = which ? neg_ind : pos_ind;
        const int pi    = ind[b * DMAX + d];
        const int valid = (pi >= 0) ? 1 : 0;
        const int piw   = valid ? pi : pi + NNODES;   // -1 -> NNODES-1
        const int deg1  = degree[sta];
        const int deg2  = degree[piw];
        const float L   = logf((float)((deg1 + 1) * (deg2 + 1)));
        int Si = 0, dsi = 0, lc = -1;
        if (valid) {
            #pragma unroll
            for (int tt = 0; tt < 8; ++tt) {
                const int l  = locations[pi * 8 + tt];
                const int x  = sh_sta[tt] ^ l;
                const int bl = bl_of(x, powlut);
                Si += bl;
                if (tt == t) { dsi = bl; lc = l; }
            }
        }
        const float lsq = L * L;
        Sarr[which][d]  = Si;
        Lsq[which][d]   = lsq;
        if (which == 0) logLsq[d] = logf(lsq);
        dsarr[which][d] = dsi;
        varr[which][d]  = valid;
        if (which == 0) ploc[d] = lc; else nloc[d] = lc;
        if (which == 0) {   // wave 0 exactly
            unsigned long long m = __ballot(valid);
            if (tid == 0) lg_sh = (float)__popcll(m);
        }
    }
    __syncthreads();

    // ---- step 2: fill base entries g in [0,16) (2048 f32 entries) ----
    // -log(p)      = logf(L^2 + y^2) - logf(L^2)
    // -log(1.1-p)  = logf(L^2 + y^2) - logf(0.1*L^2 + 1.1*y^2),  y = x + 0.1
    for (int e = tid; e < 2048; e += 256) {
        const int which = e >> 10;
        const int rem   = e & 1023;
        const int d     = rem >> 4;
        const int g     = rem & 15;
        const float lsq = Lsq[which][d];
        float x;
        if (varr[which][d])
            x = (float)(g - dsarr[which][d] + Sarr[which][d]) * 0.125f;
        else
            x = which ? 1000.0f : 0.0f;   // reference fill values
        const float y  = x + 0.1f;
        const float s  = lsq + y * y;
        const float ls = logf(s);
        float term;
        if (which) term = ls - logf(0.1f * lsq + 1.1f * y * y);
        else       term = ls - logLsq[d];
        if (which) Tn[d][g] = term; else Tp[d][g] = term;
    }
    __syncthreads();

    // ---- step 2b: pow2-corrected entries [16+r] = row[powlut[r]] ----
    for (int e = tid; e < 2048; e += 256) {
        const int which = e >> 10;
        const int rem   = e & 1023;
        const int d     = rem >> 4;
        const int r     = rem & 15;
        const int src   = powlut[r];
        if (which) Tn[d][16 + r] = Tn[d][src];
        else       Tp[d][16 + r] = Tp[d][src];
    }
    __syncthreads();

    // ---- step 3: one candidate per thread, sequential d-loop ----
    const int c = tid;
    float v = __builtin_inff();
    float plc = 0.0f, nlc = 0.0f;
    int cval = 0;
    if (c < NCAND) {
        const int q  = perm[c];
        const int st = sh_sta[t];
        if (q < NCAND - 1) {
            const int h = q / Kc, k = q % Kc;
            cval = st ^ (1 << h) ^ rmasks[((b * Hc + h) * Kc + k) * 8 + t];
        } else {
            cval = st;
        }
        float ps = 0.0f, ns = 0.0f;
        #pragma unroll 4
        for (int d = 0; d < 64; ++d) {
            const int xp = (cval ^ ploc[d]) & 0x7FFF;
            const int ip = (32 - __clz(xp)) + (((xp & (xp - 1)) == 0) ? 16 : 0);
            ps += Tp[d][ip];
            const int xn = (cval ^ nloc[d]) & 0x7FFF;
            const int in_ = (32 - __clz(xn)) + (((xn & (xn - 1)) == 0) ? 16 : 0);
            ns += Tn[d][in_];
        }
        const float lg = lg_sh;
        plc = ps / lg;            // pos_loss
        nlc = ns / lg;            // neg_loss
        v   = plc + nlc;          // total_loss (POS_RATIO == 1)
    }
    cpos[tid]    = plc;
    cneg[tid]    = nlc;
    cval_sh[tid] = cval;

    // ---- step 4: argmin over candidates (first-index tie-break) ----
    int idx = tid;
    #pragma unroll
    for (int m = 32; m >= 1; m >>= 1) {
        const float ov = __shfl_xor(v, m, 64);
        const int   oi = __shfl_xor(idx, m, 64);
        if (ov < v || (ov == v && oi < idx)) { v = ov; idx = oi; }
    }
    if ((tid & 63) == 0) { wmin[tid >> 6] = v; widx[tid >> 6] = idx; }
    __syncthreads();

    if (tid == 0) {
        float bv = wmin[0];
        int   bi = widx[0];
        #pragma unroll
        for (int w = 1; w < 4; ++w) {
            const float vv = wmin[w];
            const int   ii = widx[w];
            if (vv < bv || (vv == bv && ii < bi)) { bv = vv; bi = ii; }
        }
        const float inv = 1.0f / 1024.0f;   // mean over BATCH*TP selected values
        atomicAdd(out + 0, bv * inv);
        atomicAdd(out + 1, cpos[bi] * inv);
        atomicAdd(out + 2, cneg[bi] * inv);
        out[3 + sta * 8 + t] = (float)cval_sh[bi];   // selected location component
    }
}

extern "C" void kernel_launch(void* const* d_in, const int* in_sizes, int n_in,
                              void* d_out, int out_size, void* d_ws, size_t ws_size,
                              hipStream_t stream) {
    // setup_inputs order: lut, sta_ind, locations, degree, pos_ind, neg_ind, random_masks, perm
    const float* lut     = (const float*)d_in[0];
    const int* sta_ind   = (const int*)d_in[1];
    const int* locations = (const int*)d_in[2];
    const int* degree    = (const int*)d_in[3];
    const int* pos_ind   = (const int*)d_in[4];
    const int* neg_ind   = (const int*)d_in[5];
    const int* rmasks    = (const int*)d_in[6];
    const int* perm      = (const int*)d_in[7];
    float* out = (float*)d_out;

    hipLaunchKernelGGL(copy_kernel, dim3(1024), dim3(256), 0, stream, locations, out);
    hipLaunchKernelGGL(main_kernel, dim3(BATCH * TPC), dim3(256), 0, stream,
                       lut, sta_ind, locations, degree, pos_ind, neg_ind, rmasks, perm, out);
}

// Round 13
// 100.321 us; speedup vs baseline: 1.3622x; 1.2604x over previous
//
#include <hip/hip_runtime.h>
#include <math.h>

// Problem constants (match reference)
constexpr int TPC    = 8;       // TP
constexpr int NNODES = 100000;
constexpr int BATCH  = 128;
constexpr int DMAX   = 64;
constexpr int Hc     = 15;
constexpr int Kc     = 15;
constexpr int NCAND  = Hc * Kc + 1;   // 226

// lut[x] = f32 floor(log2(x))+1. At x=2^k a 1-ulp-low log2 can make the
// entry k instead of k+1, so the 16 entries at x in {0,1,2,4,...,2^14} are
// read from the REAL lut input (powlut); everything else is 32-__clz(x).
// (R7 passed absmax 0.0 with this fix; R8's all-f32 version also passed.)
//
// R9: replace the 3072 same-address atomicAdds (theory: serialized FP RMW
// tail ~ tens of us, shared by R7/R8, warm-replay-invariant) with per-block
// ws slots + a 1-block reduce kernel. Fuse the pow2-entry pass into step 2
// (one fewer barrier, no LDS-copy bank conflicts).

__device__ __forceinline__ int bl_of(int x, const int* __restrict__ powlut) {
    const int idx = 32 - __clz(x);              // bit_length(x), 0 for x=0
    return ((x & (x - 1)) == 0) ? powlut[idx] : idx;
}

__global__ void copy_kernel(const int* __restrict__ loc, float* __restrict__ out) {
    int i = blockIdx.x * blockDim.x + threadIdx.x;
    const int total = NNODES * TPC;
    for (int idx = i; idx < total; idx += gridDim.x * blockDim.x)
        out[3 + idx] = (float)loc[idx];
}

__launch_bounds__(256)
__global__ void main_kernel(const float* __restrict__ lut,
                            const int* __restrict__ sta_ind,
                            const int* __restrict__ locations,
                            const int* __restrict__ degree,
                            const int* __restrict__ pos_ind,
                            const int* __restrict__ neg_ind,
                            const int* __restrict__ rmasks,
                            const int* __restrict__ perm,
                            float* __restrict__ ws,
                            float* __restrict__ out) {
    // Per-(b,t) block.
    // Table layout: T[d][g], g in [0,16) = term at bit-length g (non-pow2
    // path); T[d][16+r] = term at bit-length powlut[r] (pow2 path).
    __shared__ float Tp[64][32];          // pos loss term
    __shared__ float Tn[64][32];          // neg loss term
    __shared__ int   ploc[64], nloc[64];  // t-th component of neighbor locations (-1 if invalid)
    __shared__ int   Sarr[2][64];         // dis_sta_{pos,neg}um (int, exact)
    __shared__ float Lsq[2][64];          // L^2,  L = log((deg1+1)*(deg2+1))
    __shared__ float logLsq[64];          // logf(L^2) for pos rows
    __shared__ int   dsarr[2][64];        // dis_sta_{pos,neg}[t]
    __shared__ int   varr[2][64];         // validity
    __shared__ int   sh_sta[8];
    __shared__ int   powlut[16];          // actual lut at x=0 and x=2^(i-1)
    __shared__ float lg_sh;
    __shared__ float cpos[256], cneg[256];
    __shared__ int   cval_sh[256];
    __shared__ float wmin[4];
    __shared__ int   widx[4];

    const int b   = blockIdx.x >> 3;
    const int t   = blockIdx.x & 7;
    const int tid = threadIdx.x;
    const int sta = sta_ind[b];

    if (tid < 8) sh_sta[tid] = locations[sta * 8 + tid];
    if (tid >= 16 && tid < 32) {
        const int i = tid - 16;
        powlut[i] = (i == 0) ? (int)lut[0] : (int)lut[1 << (i - 1)];
    }
    __syncthreads();

    // ---- step 1: per-d quantities (threads 0..63 pos, 64..127 neg) ----
    if (tid < 128) {
        const int which = tid >> 6;           // 0 = pos, 1 = neg
        const int d     = tid & 63;
        const int* ind  = which ? neg_ind : pos_ind;
        const int pi    = ind[b * DMAX + d];
        const int valid = (pi >= 0) ? 1 : 0;
        const int piw   = valid ? pi : pi + NNODES;   // -1 -> NNODES-1
        const int deg1  = degree[sta];
        const int deg2  = degree[piw];
        const float L   = logf((float)((deg1 + 1) * (deg2 + 1)));
        int Si = 0, dsi = 0, lc = -1;
        if (valid) {
            #pragma unroll
            for (int tt = 0; tt < 8; ++tt) {
                const int l  = locations[pi * 8 + tt];
                const int x  = sh_sta[tt] ^ l;
                const int bl = bl_of(x, powlut);
                Si += bl;
                if (tt == t) { dsi = bl; lc = l; }
            }
        }
        const float lsq = L * L;
        Sarr[which][d]  = Si;
        Lsq[which][d]   = lsq;
        if (which == 0) logLsq[d] = logf(lsq);
        dsarr[which][d] = dsi;
        varr[which][d]  = valid;
        if (which == 0) ploc[d] = lc; else nloc[d] = lc;
        if (which == 0) {   // wave 0 exactly
            unsigned long long m = __ballot(valid);
            if (tid == 0) lg_sh = (float)__popcll(m);
        }
    }
    __syncthreads();

    // ---- step 2: fill all 32 entries per (which,d) in one pass ----
    // entries [0,16): bit-length g;  [16,32): bit-length powlut[g-16]
    // -log(p)      = logf(L^2 + y^2) - logf(L^2)
    // -log(1.1-p)  = logf(L^2 + y^2) - logf(0.1*L^2 + 1.1*y^2),  y = x + 0.1
    for (int e = tid; e < 4096; e += 256) {
        const int which = e >> 11;
        const int rem   = e & 2047;
        const int d     = rem >> 5;
        const int slot  = rem & 31;
        const int g     = (slot < 16) ? slot : powlut[slot - 16];
        const float lsq = Lsq[which][d];
        float x;
        if (varr[which][d])
            x = (float)(g - dsarr[which][d] + Sarr[which][d]) * 0.125f;
        else
            x = which ? 1000.0f : 0.0f;   // reference fill values
        const float y  = x + 0.1f;
        const float s  = lsq + y * y;
        const float ls = logf(s);
        float term;
        if (which) term = ls - logf(0.1f * lsq + 1.1f * y * y);
        else       term = ls - logLsq[d];
        if (which) Tn[d][slot] = term; else Tp[d][slot] = term;
    }
    __syncthreads();

    // ---- step 3: one candidate per thread, sequential d-loop ----
    const int c = tid;
    float v = __builtin_inff();
    float plc = 0.0f, nlc = 0.0f;
    int cval = 0;
    if (c < NCAND) {
        const int q  = perm[c];
        const int st = sh_sta[t];
        if (q < NCAND - 1) {
            const int h = q / Kc, k = q % Kc;
            cval = st ^ (1 << h) ^ rmasks[((b * Hc + h) * Kc + k) * 8 + t];
        } else {
            cval = st;
        }
        float ps = 0.0f, ns = 0.0f;
        #pragma unroll 8
        for (int d = 0; d < 64; ++d) {
            const int xp = (cval ^ ploc[d]) & 0x7FFF;
            const int ip = (32 - __clz(xp)) + (((xp & (xp - 1)) == 0) ? 16 : 0);
            ps += Tp[d][ip];
            const int xn = (cval ^ nloc[d]) & 0x7FFF;
            const int in_ = (32 - __clz(xn)) + (((xn & (xn - 1)) == 0) ? 16 : 0);
            ns += Tn[d][in_];
        }
        const float lg = lg_sh;
        plc = ps / lg;            // pos_loss
        nlc = ns / lg;            // neg_loss
        v   = plc + nlc;          // total_loss (POS_RATIO == 1)
    }
    cpos[tid]    = plc;
    cneg[tid]    = nlc;
    cval_sh[tid] = cval;

    // ---- step 4: argmin over candidates (first-index tie-break) ----
    int idx = tid;
    #pragma unroll
    for (int m = 32; m >= 1; m >>= 1) {
        const float ov = __shfl_xor(v, m, 64);
        const int   oi = __shfl_xor(idx, m, 64);
        if (ov < v || (ov == v && oi < idx)) { v = ov; idx = oi; }
    }
    if ((tid & 63) == 0) { wmin[tid >> 6] = v; widx[tid >> 6] = idx; }
    __syncthreads();

    if (tid == 0) {
        float bv = wmin[0];
        int   bi = widx[0];
        #pragma unroll
        for (int w = 1; w < 4; ++w) {
            const float vv = wmin[w];
            const int   ii = widx[w];
            if (vv < bv || (vv == bv && ii < bi)) { bv = vv; bi = ii; }
        }
        // Per-block slots: no contention (R8's 3072 same-address atomicAdds
        // serialized at one L2 line -> ~tens of us tail).
        ws[blockIdx.x]          = bv;
        ws[1024 + blockIdx.x]   = cpos[bi];
        ws[2048 + blockIdx.x]   = cneg[bi];
        out[3 + sta * 8 + t]    = (float)cval_sh[bi];   // selected location component
    }
}

__launch_bounds__(256)
__global__ void reduce_kernel(const float* __restrict__ ws, float* __restrict__ out) {
    const int tid = threadIdx.x;
    __shared__ float wsum[3][4];
    #pragma unroll
    for (int a = 0; a < 3; ++a) {
        float s = 0.0f;
        #pragma unroll
        for (int j = 0; j < 4; ++j) s += ws[a * 1024 + j * 256 + tid];
        #pragma unroll
        for (int m = 32; m >= 1; m >>= 1) s += __shfl_xor(s, m, 64);
        if ((tid & 63) == 0) wsum[a][tid >> 6] = s;
    }
    __syncthreads();
    if (tid < 3)
        out[tid] = (wsum[tid][0] + wsum[tid][1] + wsum[tid][2] + wsum[tid][3])
                   * (1.0f / 1024.0f);
}

extern "C" void kernel_launch(void* const* d_in, const int* in_sizes, int n_in,
                              void* d_out, int out_size, void* d_ws, size_t ws_size,
                              hipStream_t stream) {
    // setup_inputs order: lut, sta_ind, locations, degree, pos_ind, neg_ind, random_masks, perm
    const float* lut     = (const float*)d_in[0];
    const int* sta_ind   = (const int*)d_in[1];
    const int* locations = (const int*)d_in[2];
    const int* degree    = (const int*)d_in[3];
    const int* pos_ind   = (const int*)d_in[4];
    const int* neg_ind   = (const int*)d_in[5];
    const int* rmasks    = (const int*)d_in[6];
    const int* perm      = (const int*)d_in[7];
    float* out = (float*)d_out;
    float* ws  = (float*)d_ws;

    hipLaunchKernelGGL(copy_kernel, dim3(1024), dim3(256), 0, stream, locations, out);
    hipLaunchKernelGGL(main_kernel, dim3(BATCH * TPC), dim3(256), 0, stream,
                       lut, sta_ind, locations, degree, pos_ind, neg_ind, rmasks, perm, ws, out);
    hipLaunchKernelGGL(reduce_kernel, dim3(1), dim3(256), 0, stream, ws, out);
}

// Round 14
// 95.667 us; speedup vs baseline: 1.4285x; 1.0487x over previous
//
#include <hip/hip_runtime.h>
#include <math.h>

// Problem constants (match reference)
constexpr int TPC    = 8;       // TP
constexpr int NNODES = 100000;
constexpr int BATCH  = 128;
constexpr int DMAX   = 64;
constexpr int Hc     = 15;
constexpr int Kc     = 15;
constexpr int NCAND  = Hc * Kc + 1;     // 226
constexpr int NLOCF  = NNODES * TPC;    // 800000

// lut[x] = f32 floor(log2(x))+1. At x=2^k a 1-ulp-low log2 can make the
// entry k instead of k+1, so the 16 entries at x in {0,1,2,4,...,2^14} are
// read from the REAL lut input (powlut); everything else is 32-__clz(x).
// (R7/R8/R9 passed absmax 0.0 with this fix.)
//
// R9 (passed, 100.3us total): per-block ws slots + reduce kernel removed the
// 3072 same-address atomicAdd tail (main 54.6 -> ~26us). Top-5 dispatches are
// now the harness's 256MiB d_ws re-poison fills (41us @ 81% HBM peak) - fixed
// overhead we cannot touch. R14: shrink the controllable ~26us:
//   - copy_kernel fused into main_kernel (one fewer 1024-block launch;
//     selected-row writes moved to the 1-block finish kernel -> no race)
//   - invalid rows store loc=0 (index-constant table rows) -> no & masks
//   - int4 loads for the 32B neighbor rows in step 1

__launch_bounds__(256)
__global__ void main_kernel(const float* __restrict__ lut,
                            const int* __restrict__ sta_ind,
                            const int* __restrict__ locations,
                            const int* __restrict__ degree,
                            const int* __restrict__ pos_ind,
                            const int* __restrict__ neg_ind,
                            const int* __restrict__ rmasks,
                            const int* __restrict__ perm,
                            float* __restrict__ wsf,
                            int*   __restrict__ wsi,
                            float* __restrict__ out) {
    // Per-(b,t) block.
    // Table layout: T[d][g], g in [0,16) = term at bit-length g (non-pow2
    // path); T[d][16+r] = term at bit-length powlut[r] (pow2 path).
    __shared__ float Tp[64][32];          // pos loss term
    __shared__ float Tn[64][32];          // neg loss term
    __shared__ int   ploc[64], nloc[64];  // t-th component of neighbor locations (0 if invalid)
    __shared__ int   Sarr[2][64];         // dis_sta_{pos,neg}um (int, exact)
    __shared__ float Lsq[2][64];          // L^2,  L = log((deg1+1)*(deg2+1))
    __shared__ float logLsq[64];          // logf(L^2) for pos rows
    __shared__ int   dsarr[2][64];        // dis_sta_{pos,neg}[t]
    __shared__ int   varr[2][64];         // validity
    __shared__ int   sh_sta[8];
    __shared__ int   powlut[16];          // actual lut at x=0 and x=2^(i-1)
    __shared__ float lg_sh;
    __shared__ float cpos[256], cneg[256];
    __shared__ int   cval_sh[256];
    __shared__ float wmin[4];
    __shared__ int   widx[4];

    const int bid = blockIdx.x;
    const int b   = bid >> 3;
    const int t   = bid & 7;
    const int tid = threadIdx.x;
    const int sta = sta_ind[b];

    // Fused locations -> out[3..] copy (grid-stride slice, ~3 elems/thread).
    // Selected rows are overwritten later by finish_kernel (stream-ordered).
    for (int idx = bid * 256 + tid; idx < NLOCF; idx += 1024 * 256)
        out[3 + idx] = (float)locations[idx];

    if (tid < 8) sh_sta[tid] = locations[sta * 8 + tid];
    if (tid >= 16 && tid < 32) {
        const int i = tid - 16;
        powlut[i] = (i == 0) ? (int)lut[0] : (int)lut[1 << (i - 1)];
    }
    __syncthreads();

    // ---- step 1: per-d quantities (threads 0..63 pos, 64..127 neg) ----
    if (tid < 128) {
        const int which = tid >> 6;           // 0 = pos, 1 = neg
        const int d     = tid & 63;
        const int* ind  = which ? neg_ind : pos_ind;
        const int pi    = ind[b * DMAX + d];
        const int valid = (pi >= 0) ? 1 : 0;
        const int piw   = valid ? pi : pi + NNODES;   // -1 -> NNODES-1
        const int deg1  = degree[sta];
        const int deg2  = degree[piw];
        const float L   = logf((float)((deg1 + 1) * (deg2 + 1)));
        int Si = 0, dsi = 0, lc = 0;          // lc=0 for invalid: in-range index,
                                              // and the row is g-constant anyway
        if (valid) {
            const int4* lp = reinterpret_cast<const int4*>(locations + pi * 8);
            const int4 va = lp[0], vb = lp[1];
            const int l0[8] = {va.x, va.y, va.z, va.w, vb.x, vb.y, vb.z, vb.w};
            #pragma unroll
            for (int tt = 0; tt < 8; ++tt) {
                const int x   = sh_sta[tt] ^ l0[tt];
                const int idx = 32 - __clz(x);
                const int bl  = ((x & (x - 1)) == 0) ? powlut[idx] : idx;
                Si += bl;
                if (tt == t) { dsi = bl; lc = l0[tt]; }
            }
        }
        const float lsq = L * L;
        Sarr[which][d]  = Si;
        Lsq[which][d]   = lsq;
        if (which == 0) logLsq[d] = logf(lsq);
        dsarr[which][d] = dsi;
        varr[which][d]  = valid;
        if (which == 0) ploc[d] = lc; else nloc[d] = lc;
        if (which == 0) {   // wave 0 exactly
            unsigned long long m = __ballot(valid);
            if (tid == 0) lg_sh = (float)__popcll(m);
        }
    }
    __syncthreads();

    // ---- step 2: fill all 32 entries per (which,d) in one pass ----
    // entries [0,16): bit-length g;  [16,32): bit-length powlut[g-16]
    // -log(p)      = logf(L^2 + y^2) - logf(L^2)
    // -log(1.1-p)  = logf(L^2 + y^2) - logf(0.1*L^2 + 1.1*y^2),  y = x + 0.1
    for (int e = tid; e < 4096; e += 256) {
        const int which = e >> 11;
        const int rem   = e & 2047;
        const int d     = rem >> 5;
        const int slot  = rem & 31;
        const int g     = (slot < 16) ? slot : powlut[slot - 16];
        const float lsq = Lsq[which][d];
        float x;
        if (varr[which][d])
            x = (float)(g - dsarr[which][d] + Sarr[which][d]) * 0.125f;
        else
            x = which ? 1000.0f : 0.0f;   // reference fill values
        const float y  = x + 0.1f;
        const float s  = lsq + y * y;
        const float ls = logf(s);
        float term;
        if (which) term = ls - logf(0.1f * lsq + 1.1f * y * y);
        else       term = ls - logLsq[d];
        if (which) Tn[d][slot] = term; else Tp[d][slot] = term;
    }
    __syncthreads();

    // ---- step 3: one candidate per thread, sequential d-loop ----
    const int c = tid;
    float v = __builtin_inff();
    float plc = 0.0f, nlc = 0.0f;
    int cval = 0;
    if (c < NCAND) {
        const int q  = perm[c];
        const int st = sh_sta[t];
        if (q < NCAND - 1) {
            const int h = q / Kc, k = q % Kc;
            cval = st ^ (1 << h) ^ rmasks[((b * Hc + h) * Kc + k) * 8 + t];
        } else {
            cval = st;
        }
        float ps = 0.0f, ns = 0.0f;
        #pragma unroll 8
        for (int d = 0; d < 64; ++d) {
            const int xp = cval ^ ploc[d];
            const int bp = 32 - __clz(xp);
            ps += Tp[d][((xp & (xp - 1)) == 0) ? bp + 16 : bp];
            const int xn = cval ^ nloc[d];
            const int bn = 32 - __clz(xn);
            ns += Tn[d][((xn & (xn - 1)) == 0) ? bn + 16 : bn];
        }
        const float lg = lg_sh;
        plc = ps / lg;            // pos_loss
        nlc = ns / lg;            // neg_loss
        v   = plc + nlc;          // total_loss (POS_RATIO == 1)
    }
    cpos[tid]    = plc;
    cneg[tid]    = nlc;
    cval_sh[tid] = cval;

    // ---- step 4: argmin over candidates (first-index tie-break) ----
    int idx = tid;
    #pragma unroll
    for (int m = 32; m >= 1; m >>= 1) {
        const float ov = __shfl_xor(v, m, 64);
        const int   oi = __shfl_xor(idx, m, 64);
        if (ov < v || (ov == v && oi < idx)) { v = ov; idx = oi; }
    }
    if ((tid & 63) == 0) { wmin[tid >> 6] = v; widx[tid >> 6] = idx; }
    __syncthreads();

    if (tid == 0) {
        float bv = wmin[0];
        int   bi = widx[0];
        #pragma unroll
        for (int w = 1; w < 4; ++w) {
            const float vv = wmin[w];
            const int   ii = widx[w];
            if (vv < bv || (vv == bv && ii < bi)) { bv = vv; bi = ii; }
        }
        wsf[bid]        = bv;
        wsf[1024 + bid] = cpos[bi];
        wsf[2048 + bid] = cneg[bi];
        wsi[bid]        = cval_sh[bi];
    }
}

__launch_bounds__(256)
__global__ void finish_kernel(const int* __restrict__ sta_ind,
                              const float* __restrict__ wsf,
                              const int* __restrict__ wsi,
                              float* __restrict__ out) {
    const int tid = threadIdx.x;
    __shared__ float wsum[3][4];
    #pragma unroll
    for (int a = 0; a < 3; ++a) {
        float s = 0.0f;
        #pragma unroll
        for (int j = 0; j < 4; ++j) s += wsf[a * 1024 + j * 256 + tid];
        #pragma unroll
        for (int m = 32; m >= 1; m >>= 1) s += __shfl_xor(s, m, 64);
        if ((tid & 63) == 0) wsum[a][tid >> 6] = s;
    }
    // Scatter the 1024 selected location components (after all main blocks).
    #pragma unroll
    for (int j = 0; j < 4; ++j) {
        const int i = j * 256 + tid;          // (b,t) flat index
        const int b = i >> 3, t = i & 7;
        out[3 + sta_ind[b] * 8 + t] = (float)wsi[i];
    }
    __syncthreads();
    if (tid < 3)
        out[tid] = (wsum[tid][0] + wsum[tid][1] + wsum[tid][2] + wsum[tid][3])
                   * (1.0f / 1024.0f);
}

extern "C" void kernel_launch(void* const* d_in, const int* in_sizes, int n_in,
                              void* d_out, int out_size, void* d_ws, size_t ws_size,
                              hipStream_t stream) {
    // setup_inputs order: lut, sta_ind, locations, degree, pos_ind, neg_ind, random_masks, perm
    const float* lut     = (const float*)d_in[0];
    const int* sta_ind   = (const int*)d_in[1];
    const int* locations = (const int*)d_in[2];
    const int* degree    = (const int*)d_in[3];
    const int* pos_ind   = (const int*)d_in[4];
    const int* neg_ind   = (const int*)d_in[5];
    const int* rmasks    = (const int*)d_in[6];
    const int* perm      = (const int*)d_in[7];
    float* out = (float*)d_out;
    float* wsf = (float*)d_ws;
    int*   wsi = (int*)d_ws + 3072;

    hipLaunchKernelGGL(main_kernel, dim3(BATCH * TPC), dim3(256), 0, stream,
                       lut, sta_ind, locations, degree, pos_ind, neg_ind, rmasks, perm,
                       wsf, wsi, out);
    hipLaunchKernelGGL(finish_kernel, dim3(1), dim3(256), 0, stream,
                       sta_ind, wsf, wsi, out);
}